// Round 5
// baseline (232.172 us; speedup 1.0000x reference)
//
#include <hip/hip_runtime.h>
#include <cstdint>
#include <cstddef>

#define N1 4096
#define N2 16384
#define C1 256
#define C2 128
#define HH 256
#define K1 384
#define BQ 32768          // B*N2 total queries
#define KPAD 392          // LDS k-stride (bf16 elems): 16B-aligned, banks balanced
#define NCH 2             // k_nn point chunks (2048 points each)

typedef float  f32x4  __attribute__((ext_vector_type(4)));
typedef __bf16 bf16x8 __attribute__((ext_vector_type(8)));
typedef __bf16 bf16x4 __attribute__((ext_vector_type(4)));

// ---------------------------------------------------------------------------
// k_prep: pack points1 into pair-SoA [x0 x1 y0 y1 z0 z1 w0 w1] per 2 points,
// exact RN |k|^2; convert W1/W2 to bf16; fold BN into per-row scale/shift.
// ---------------------------------------------------------------------------
__global__ __launch_bounds__(256) void k_prep(
    const float* __restrict__ p1,
    const float* __restrict__ W1, const float* __restrict__ W2,
    const float* __restrict__ b1, const float* __restrict__ g1,
    const float* __restrict__ be1, const float* __restrict__ mm1,
    const float* __restrict__ vv1,
    const float* __restrict__ b2, const float* __restrict__ g2,
    const float* __restrict__ be2, const float* __restrict__ mm2,
    const float* __restrict__ vv2,
    float* __restrict__ pts8, __bf16* __restrict__ W1b,
    __bf16* __restrict__ W2b, float* __restrict__ scsh) {
  int idx = blockIdx.x * 256 + threadIdx.x;      // grid 384*256 = 98304
  if (idx < HH * K1) W1b[idx] = (__bf16)W1[idx];
  if (idx < HH * HH) W2b[idx] = (__bf16)W2[idx];
  if (idx < 2 * N1) {
    int b = idx >> 12, j = idx & (N1 - 1);
    const float* p = p1 + (size_t)b * 3 * N1;
    float x = p[j], y = p[N1 + j], z = p[2 * N1 + j];
    float sk = __fadd_rn(__fadd_rn(__fmul_rn(x, x), __fmul_rn(y, y)),
                         __fmul_rn(z, z));
    size_t base = ((size_t)b * (N1 / 2) + (j >> 1)) * 8 + (j & 1);
    pts8[base + 0] = x;
    pts8[base + 2] = y;
    pts8[base + 4] = z;
    pts8[base + 6] = sk;
  }
  if (idx < HH) {
    float sc = g1[idx] / sqrtf(vv1[idx] + 1e-3f);
    scsh[idx]          = sc;
    scsh[HH + idx]     = fmaf(b1[idx] - mm1[idx], sc, be1[idx]);
    float s2 = g2[idx] / sqrtf(vv2[idx] + 1e-3f);
    scsh[2 * HH + idx] = s2;
    scsh[3 * HH + idx] = fmaf(b2[idx] - mm2[idx], s2, be2[idx]);
  }
}

// Select-based stable top-3 insert (strict <: earliest index wins ties).
#define INS(da, db, dc, ia, ib, ic, dd, jj)                                    \
  {                                                                            \
    bool ca = (dd) < (da), cb = (dd) < (db), cc = (dd) < (dc);                 \
    dc = cb ? (db) : (cc ? (dd) : (dc));                                       \
    ic = cb ? (ib) : (cc ? (jj) : (ic));                                       \
    db = ca ? (da) : (cb ? (dd) : (db));                                       \
    ib = ca ? (ia) : (cb ? (jj) : (ib));                                       \
    da = ca ? (dd) : (da);                                                     \
    ia = ca ? (jj) : (ia);                                                     \
  }

// Hot-loop insert: values via min/med3 (3 ops, == sorted insert), indices via
// strict-< masks (stable, earliest index wins ties). Identity when dd >= dc.
#define INS3(da, db, dc, ia, ib, ic, dd, jj)                                   \
  {                                                                            \
    bool ca = (dd) < (da), cb = (dd) < (db), cc = (dd) < (dc);                 \
    float ndb = __builtin_amdgcn_fmed3f((da), (dd), (db));                     \
    float ndc = __builtin_amdgcn_fmed3f((db), (dd), (dc));                     \
    float nda = fminf((da), (dd));                                             \
    int nic = cb ? (ib) : (cc ? (jj) : (ic));                                  \
    int nib = ca ? (ia) : (cb ? (jj) : (ib));                                  \
    int nia = ca ? (jj) : (ia);                                                \
    da = nda; db = ndb; dc = ndc; ia = nia; ib = nib; ic = nic;                \
  }

// Lexicographic (d, idx) insert — for merging chains whose order isn't index
// order.
#define LEXINS(da, db, dc, ia, ib, ic, dd, jj)                                 \
  {                                                                            \
    bool ca = ((dd) < (da)) || ((dd) == (da) && (jj) < (ia));                  \
    bool cb = ((dd) < (db)) || ((dd) == (db) && (jj) < (ib));                  \
    bool cc = ((dd) < (dc)) || ((dd) == (dc) && (jj) < (ic));                  \
    dc = cb ? (db) : (cc ? (dd) : (dc));                                       \
    ic = cb ? (ib) : (cc ? (jj) : (ic));                                       \
    db = ca ? (da) : (cb ? (dd) : (db));                                       \
    ib = ca ? (ia) : (cb ? (jj) : (ib));                                       \
    da = ca ? (dd) : (da);                                                     \
    ia = ca ? (jj) : (ia);                                                     \
  }

// ---------------------------------------------------------------------------
// k_nn: 3-NN with wave-uniform branch-skip of the insert.
// 256 blocks = 128 query-tiles x 2 point-chunks of 2048 -> exactly 1 block/CU,
// 1 wave/SIMD. Two independent top-3 chains (even/odd points); the 11-op
// insert runs only when __ballot says some lane inserts (insert is provably
// identity otherwise); expected taken fraction ~50%. Distance arithmetic is
// the exact RN sequence of the reference: dd = fma(dot,-2,rn(su+sk)) ==
// rn(rn(su+sk) - rn(2*dot)) since -2*dot is exact.
// ---------------------------------------------------------------------------
__global__ __launch_bounds__(256) void k_nn(
    const float* __restrict__ p2, const float4* __restrict__ pts8,
    float* __restrict__ pd, unsigned short* __restrict__ pi) {
#pragma clang fp contract(off)
  const int bx = blockIdx.x;
  const int ch = bx & (NCH - 1);
  const int qt = bx >> 1;            // 0..127
  const int b  = qt >> 6;            // uniform per block
  const int n  = ((qt & 63) << 8) + threadIdx.x;

  const float* p2b = p2 + (size_t)b * 3 * N2;
  float ux = p2b[n], uy = p2b[N2 + n], uz = p2b[2 * N2 + n];
  float su = __fadd_rn(__fadd_rn(__fmul_rn(ux, ux), __fmul_rn(uy, uy)),
                       __fmul_rn(uz, uz));

  // pair-SoA: 2 float4 per point-pair; chunk = 1024 pairs
  const float4* pp = pts8 + ((size_t)b * (N1 / 2) + ch * 1024) * 2;
  const int j0 = ch * 2048;
  float daA = 3.0e38f, dbA = 3.0e38f, dcA = 3.0e38f;
  float daB = 3.0e38f, dbB = 3.0e38f, dcB = 3.0e38f;
  int iaA = 0, ibA = 0, icA = 0, iaB = 0, ibB = 0, icB = 0;
#pragma unroll 4
  for (int k = 0; k < 1024; ++k) {
    float4 q0 = pp[2 * k];           // x0 x1 y0 y1
    float4 q1 = pp[2 * k + 1];       // z0 z1 w0 w1
    float dotA = __fadd_rn(__fadd_rn(__fmul_rn(ux, q0.x), __fmul_rn(uy, q0.z)),
                           __fmul_rn(uz, q1.x));
    float ddA = __builtin_fmaf(dotA, -2.0f, __fadd_rn(su, q1.z));
    float dotB = __fadd_rn(__fadd_rn(__fmul_rn(ux, q0.y), __fmul_rn(uy, q0.w)),
                           __fmul_rn(uz, q1.y));
    float ddB = __builtin_fmaf(dotB, -2.0f, __fadd_rn(su, q1.w));
    // wave-uniform skip: INS3 is identity unless dd < dc for some lane
    if (__ballot((ddA < dcA) || (ddB < dcB))) {
      INS3(daA, dbA, dcA, iaA, ibA, icA, ddA, j0 + 2 * k);
      INS3(daB, dbB, dcB, iaB, ibB, icB, ddB, j0 + 2 * k + 1);
    }
  }
  // merge chain B into chain A with (d, idx) lexicographic order
  LEXINS(daA, dbA, dcA, iaA, ibA, icA, daB, iaB);
  LEXINS(daA, dbA, dcA, iaA, ibA, icA, dbB, ibB);
  LEXINS(daA, dbA, dcA, iaA, ibA, icA, dcB, icB);

  // coalesced [ch][k][q] planes
  int q = b * N2 + n;
  pd[(ch * 3 + 0) * BQ + q] = daA;
  pd[(ch * 3 + 1) * BQ + q] = dbA;
  pd[(ch * 3 + 2) * BQ + q] = dcA;
  pi[(ch * 3 + 0) * BQ + q] = (unsigned short)iaA;
  pi[(ch * 3 + 1) * BQ + q] = (unsigned short)ibA;
  pi[(ch * 3 + 2) * BQ + q] = (unsigned short)icA;
}

// ---------------------------------------------------------------------------
// k_merge: combine NCH chunk-partial top-3s (chunk order == index order and
// each partial is (d,idx)-sorted, so plain strict-< insertion reproduces
// stable top-k), then the exact reference weight arithmetic.
// ---------------------------------------------------------------------------
__global__ __launch_bounds__(256) void k_merge(
    const float* __restrict__ pd, const unsigned short* __restrict__ pi,
    float* __restrict__ wbuf, int* __restrict__ ibuf) {
  int q = blockIdx.x * 256 + threadIdx.x;    // 128 blocks
  float da = 3.0e38f, db = 3.0e38f, dc = 3.0e38f;
  int ia = 0, ib = 0, ic = 0;
#pragma unroll
  for (int ch = 0; ch < NCH; ++ch) {
#pragma unroll
    for (int k = 0; k < 3; ++k) {
      float dd = pd[(ch * 3 + k) * BQ + q];
      int jj = (int)pi[(ch * 3 + k) * BQ + q];
      INS(da, db, dc, ia, ib, ic, dd, jj);
    }
  }
  float qa = fmaxf(da, 0.0f), qb = fmaxf(db, 0.0f), qc = fmaxf(dc, 0.0f);
  qa = fmaxf(__fmul_rn(qa, qa), 1e-10f);
  qb = fmaxf(__fmul_rn(qb, qb), 1e-10f);
  qc = fmaxf(__fmul_rn(qc, qc), 1e-10f);
  float va = __fdiv_rn(1.0f, qa);
  float vb = __fdiv_rn(1.0f, qb);
  float vc = __fdiv_rn(1.0f, qc);
  float s = __fadd_rn(__fadd_rn(va, vb), vc);
  wbuf[q]           = __fdiv_rn(va, s);
  wbuf[BQ + q]      = __fdiv_rn(vb, s);
  wbuf[2 * BQ + q]  = __fdiv_rn(vc, s);
  ibuf[q]          = ia;
  ibuf[BQ + q]     = ib;
  ibuf[2 * BQ + q] = ic;
}

// ---------------------------------------------------------------------------
// k_transpose: features1 [B,C1,N1] -> f1T [B,N1,C1] (contiguous gather rows).
// ---------------------------------------------------------------------------
__global__ __launch_bounds__(256) void k_transpose(
    const float* __restrict__ f1, float* __restrict__ f1T) {
  __shared__ float tile[64][65];
  const int bx = blockIdx.x;            // B * 4(ct) * 64(nt) = 512
  const int b = bx >> 8;
  const int rest = bx & 255;
  const int ct = rest >> 6;
  const int ntb = (rest & 63) << 6;
  const int t = threadIdx.x;
  const int ln = t & 63, g = t >> 6;

  const float* src = f1 + ((size_t)b * C1 + ct * 64) * N1 + ntb;
  for (int k = 0; k < 16; ++k) {
    int c = (k << 2) + g;
    tile[c][ln] = src[(size_t)c * N1 + ln];
  }
  __syncthreads();
  float* dst = f1T + ((size_t)b * N1 + ntb) * C1 + ct * 64;
  for (int k = 0; k < 16; ++k) {
    int nn = (k << 2) + g;
    dst[(size_t)nn * C1 + ln] = tile[ln][nn];
  }
}

// ---------------------------------------------------------------------------
// k_fused: gather+interp -> bf16 LDS [col][k] -> MFMA GEMM1 -> BN1+ReLU ->
// bf16 LDS h -> MFMA GEMM2 -> BN2+ReLU -> out (fp32).
// 256 threads = 4 waves; wave wv owns output rows [wv*64, wv*64+64), all 64
// cols of the block's n-tile: 4x4 tiles of mfma_f32_16x16x32_bf16.
// ---------------------------------------------------------------------------
__global__ __launch_bounds__(256) void k_fused(
    const float* __restrict__ f1T, const float* __restrict__ f2,
    const float* __restrict__ wbuf, const int* __restrict__ ibuf,
    const __bf16* __restrict__ W1b, const __bf16* __restrict__ W2b,
    const float* __restrict__ scsh, float* __restrict__ out) {
  __shared__ __bf16 sX[64 * KPAD];       // 49KB; x for GEMM1, then h for GEMM2
  const int t = threadIdx.x;
  const int bx = blockIdx.x;
  const int b = bx >> 8;
  const int n0 = (bx & 255) << 6;

  // ---- Phase A1: interp C1 channels (k = 0..255) ----
  {
    const int nn = t >> 2, qq = t & 3;   // 4 threads per column
    const int gi = b * N2 + n0 + nn;
    const float w0 = wbuf[gi], w1 = wbuf[BQ + gi], w2 = wbuf[2 * BQ + gi];
    const int i0 = ibuf[gi], i1 = ibuf[BQ + gi], i2 = ibuf[2 * BQ + gi];
    const float4* r0 = (const float4*)(f1T + ((size_t)b * N1 + i0) * C1);
    const float4* r1 = (const float4*)(f1T + ((size_t)b * N1 + i1) * C1);
    const float4* r2 = (const float4*)(f1T + ((size_t)b * N1 + i2) * C1);
#pragma unroll 4
    for (int m = 0; m < 16; ++m) {
      int idx4 = (qq << 4) + m;
      float4 a = r0[idx4], c4 = r1[idx4], d4 = r2[idx4];
      bf16x4 v;
      v[0] = (__bf16)fmaf(w0, a.x, fmaf(w1, c4.x, w2 * d4.x));
      v[1] = (__bf16)fmaf(w0, a.y, fmaf(w1, c4.y, w2 * d4.y));
      v[2] = (__bf16)fmaf(w0, a.z, fmaf(w1, c4.z, w2 * d4.z));
      v[3] = (__bf16)fmaf(w0, a.w, fmaf(w1, c4.w, w2 * d4.w));
      *(bf16x4*)&sX[nn * KPAD + (idx4 << 2)] = v;
    }
  }
  // ---- Phase A2: features2 channels (k = 256..383) ----
  {
    const int col = t & 63, g = t >> 6;
    const float* f2b = f2 + (size_t)b * C2 * N2 + n0 + col;
#pragma unroll 2
    for (int m = 0; m < 8; ++m) {
      int c4 = (g << 5) + (m << 2);
      bf16x4 v;
      v[0] = (__bf16)f2b[(size_t)(c4 + 0) * N2];
      v[1] = (__bf16)f2b[(size_t)(c4 + 1) * N2];
      v[2] = (__bf16)f2b[(size_t)(c4 + 2) * N2];
      v[3] = (__bf16)f2b[(size_t)(c4 + 3) * N2];
      *(bf16x4*)&sX[col * KPAD + 256 + c4] = v;
    }
  }
  __syncthreads();

  const int l  = t & 63;
  const int wv = __builtin_amdgcn_readfirstlane(t >> 6);
  const int ob = wv << 6;
  const int lm = l & 15, lg = l >> 4;

  f32x4 acc[4][4];
#pragma unroll
  for (int mt = 0; mt < 4; ++mt)
#pragma unroll
    for (int nt = 0; nt < 4; ++nt) acc[mt][nt] = (f32x4)0.0f;

  // ---- GEMM1: K = 384 (12 k-steps) ----
  for (int ks = 0; ks < 12; ++ks) {
    bf16x8 af[4], bfr[4];
#pragma unroll
    for (int mt = 0; mt < 4; ++mt)
      af[mt] = *(const bf16x8*)(W1b + (size_t)(ob + mt * 16 + lm) * K1 +
                                ks * 32 + lg * 8);
#pragma unroll
    for (int nt = 0; nt < 4; ++nt)
      bfr[nt] = *(const bf16x8*)&sX[(nt * 16 + lm) * KPAD + ks * 32 + lg * 8];
#pragma unroll
    for (int mt = 0; mt < 4; ++mt)
#pragma unroll
      for (int nt = 0; nt < 4; ++nt)
        acc[mt][nt] = __builtin_amdgcn_mfma_f32_16x16x32_bf16(
            af[mt], bfr[nt], acc[mt][nt], 0, 0, 0);
  }
  __syncthreads();

  // ---- BN1 + ReLU -> h (bf16) back into sX ----
#pragma unroll
  for (int mt = 0; mt < 4; ++mt) {
    int rb = ob + mt * 16 + lg * 4;     // h-channel base (GEMM1 output row)
    float4 sc4 = *(const float4*)(scsh + rb);
    float4 sh4 = *(const float4*)(scsh + HH + rb);
#pragma unroll
    for (int nt = 0; nt < 4; ++nt) {
      int colc = nt * 16 + lm;
      bf16x4 v;
      v[0] = (__bf16)fmaxf(fmaf(acc[mt][nt][0], sc4.x, sh4.x), 0.0f);
      v[1] = (__bf16)fmaxf(fmaf(acc[mt][nt][1], sc4.y, sh4.y), 0.0f);
      v[2] = (__bf16)fmaxf(fmaf(acc[mt][nt][2], sc4.z, sh4.z), 0.0f);
      v[3] = (__bf16)fmaxf(fmaf(acc[mt][nt][3], sc4.w, sh4.w), 0.0f);
      *(bf16x4*)&sX[colc * KPAD + rb] = v;
    }
  }
  __syncthreads();

  // ---- GEMM2: K = 256 (8 k-steps) ----
  f32x4 ac2[4][4];
#pragma unroll
  for (int mt = 0; mt < 4; ++mt)
#pragma unroll
    for (int nt = 0; nt < 4; ++nt) ac2[mt][nt] = (f32x4)0.0f;
  for (int ks = 0; ks < 8; ++ks) {
    bf16x8 af[4], bfr[4];
#pragma unroll
    for (int mt = 0; mt < 4; ++mt)
      af[mt] = *(const bf16x8*)(W2b + (size_t)(ob + mt * 16 + lm) * HH +
                                ks * 32 + lg * 8);
#pragma unroll
    for (int nt = 0; nt < 4; ++nt)
      bfr[nt] = *(const bf16x8*)&sX[(nt * 16 + lm) * KPAD + ks * 32 + lg * 8];
#pragma unroll
    for (int mt = 0; mt < 4; ++mt)
#pragma unroll
      for (int nt = 0; nt < 4; ++nt)
        ac2[mt][nt] = __builtin_amdgcn_mfma_f32_16x16x32_bf16(
            af[mt], bfr[nt], ac2[mt][nt], 0, 0, 0);
  }

  // ---- BN2 + ReLU -> out (fp32) ----
  float* outb = out + (size_t)b * HH * N2 + n0;
#pragma unroll
  for (int mt = 0; mt < 4; ++mt) {
    int rb = ob + mt * 16 + lg * 4;
    float4 sc4 = *(const float4*)(scsh + 2 * HH + rb);
    float4 sh4 = *(const float4*)(scsh + 3 * HH + rb);
#pragma unroll
    for (int nt = 0; nt < 4; ++nt) {
      int colc = nt * 16 + lm;
      outb[(size_t)(rb + 0) * N2 + colc] =
          fmaxf(fmaf(ac2[mt][nt][0], sc4.x, sh4.x), 0.0f);
      outb[(size_t)(rb + 1) * N2 + colc] =
          fmaxf(fmaf(ac2[mt][nt][1], sc4.y, sh4.y), 0.0f);
      outb[(size_t)(rb + 2) * N2 + colc] =
          fmaxf(fmaf(ac2[mt][nt][2], sc4.z, sh4.z), 0.0f);
      outb[(size_t)(rb + 3) * N2 + colc] =
          fmaxf(fmaf(ac2[mt][nt][3], sc4.w, sh4.w), 0.0f);
    }
  }
}

// ---------------------------------------------------------------------------
extern "C" void kernel_launch(void* const* d_in, const int* in_sizes, int n_in,
                              void* d_out, int out_size, void* d_ws, size_t ws_size,
                              hipStream_t stream) {
  const float* p1  = (const float*)d_in[0];
  const float* p2  = (const float*)d_in[1];
  const float* f1  = (const float*)d_in[2];
  const float* f2  = (const float*)d_in[3];
  const float* W1  = (const float*)d_in[4];
  const float* bb1 = (const float*)d_in[5];
  const float* g1  = (const float*)d_in[6];
  const float* be1 = (const float*)d_in[7];
  const float* mm1 = (const float*)d_in[8];
  const float* vv1 = (const float*)d_in[9];
  const float* W2  = (const float*)d_in[10];
  const float* bb2 = (const float*)d_in[11];
  const float* g2  = (const float*)d_in[12];
  const float* be2 = (const float*)d_in[13];
  const float* mm2 = (const float*)d_in[14];
  const float* vv2 = (const float*)d_in[15];
  float* out = (float*)d_out;

  // ws layout (no aliasing; ~10.8 MB total)
  char* ws = (char*)d_ws;
  float*          f1T  = (float*)(ws);                 // 8,388,608 B
  float*          wbuf = (float*)(ws + 8388608);       //   393,216 B
  int*            ibuf = (int*)  (ws + 8781824);       //   393,216 B
  float*          pts8 = (float*)(ws + 9175040);       //   131,072 B
  __bf16*         W1b  = (__bf16*)(ws + 9306112);      //   196,608 B
  __bf16*         W2b  = (__bf16*)(ws + 9502720);      //   131,072 B
  float*          scsh = (float*)(ws + 9633792);       //     4,096 B
  float*          pd   = (float*)(ws + 9637888);       //   786,432 B
  unsigned short* pi   = (unsigned short*)(ws + 10424320); // 393,216 B

  k_prep<<<384, 256, 0, stream>>>(p1, W1, W2,
                                  bb1, g1, be1, mm1, vv1,
                                  bb2, g2, be2, mm2, vv2,
                                  pts8, W1b, W2b, scsh);
  k_nn<<<256, 256, 0, stream>>>(p2, (const float4*)pts8, pd, pi);
  k_merge<<<128, 256, 0, stream>>>(pd, pi, wbuf, ibuf);
  k_transpose<<<512, 256, 0, stream>>>(f1, f1T);
  k_fused<<<512, 256, 0, stream>>>(f1T, f2, wbuf, ibuf, W1b, W2b, scsh, out);
}